// Round 13
// baseline (88.935 us; speedup 1.0000x reference)
//
#include <hip/hip_runtime.h>

// Problem constants: x [32,112,112,128] fp32, W [7,7,2,1] HWIO, b [1]
static constexpr int Bn = 32;
static constexpr int Hn = 112;
static constexpr int Wn = 112;
static constexpr int HALO = 3;
static constexpr int NROWS = Bn * Hn;          // 3584 blocks, block = one image row
static constexpr int SPIN_MAX = 400;           // with s_sleep(4): ~43us cap, then fallback

typedef float floatx4 __attribute__((ext_vector_type(4)));

union f2u { float2 f; unsigned long long u; };

// ---------------------------------------------------------------------------
// R12 structure (85.1us best) with P2 restructured for overlap:
// per-32-lane-group ownership of stats-window rows. Group g polls row g's
// flag (s_sleep(4) backoff) then immediately loads that row's stats into
// LDS — backward rows (r-3..r-1, always published by first check) load
// WHILE forward-dep groups (r+1..r+3) sleep, instead of the whole block
// stalling at a barrier for the slowest flag. One barrier eliminated.
//
//  P0: own-row x -> registers (14 float4/thread), issued first.
//  P1: stats from regs -> LDS + global (relaxed u64, no cache maintenance);
//      pin regs with asm; s_waitcnt vmcnt(0) + barrier; publish flag.
//  P2: merged poll+load per group; rare timeout -> cooperative recompute.
//  P3: 7x7x2 conv + bias + sigmoid -> gate in LDS.
//  P4: out = x(reg) * gate, non-temporal store. x never re-read.
// ---------------------------------------------------------------------------
__global__ __launch_bounds__(256) void fused_reg_kernel(const float* __restrict__ x,
                                                        const float* __restrict__ Wc,
                                                        const float* __restrict__ bias,
                                                        unsigned long long* __restrict__ stats,
                                                        int* __restrict__ flags,
                                                        float* __restrict__ out) {
    __shared__ float2 sdat[7][Wn + 2 * HALO];  // zero-padded stat tile (6.6 KB)
    __shared__ float  glds[Wn];
    __shared__ float  w[98];
    __shared__ int    rowstate[7];             // 0=own,1=loaded,2=zero,3=recompute

    const int wid  = blockIdx.x;               // == b*Hn + r
    const int b    = wid / Hn;
    const int r    = wid % Hn;
    const int tid  = threadIdx.x;
    const int lane = tid & 31;
    const int grp  = tid >> 5;                 // 8 groups; group = one pixel (32 float4)

    const floatx4* __restrict__ x4 = reinterpret_cast<const floatx4*>(x);
    const size_t rowbase = (size_t)wid * Wn * 32;        // float4 units

    // ---- P0: own-row x -> registers (issued first, hides HBM latency) -----
    float xa[14], xb[14], xc[14], xd[14];
#pragma unroll
    for (int j = 0; j < 14; ++j) {
        const int c = grp + 8 * j;
        const floatx4 v = x4[rowbase + (size_t)c * 32 + lane];
        xa[j] = v.x; xb[j] = v.y; xc[j] = v.z; xd[j] = v.w;
    }

    if (tid < 98) w[tid] = Wc[tid];
    for (int i = tid; i < 7 * (Wn + 2 * HALO); i += 256)
        ((float2*)sdat)[i] = make_float2(0.f, 0.f);
    __syncthreads();

    // ---- P1: own-row stats from registers -> LDS + global (relaxed) -------
#pragma unroll
    for (int j = 0; j < 14; ++j) {
        const int c = grp + 8 * j;
        float s = xa[j] + xb[j] + xc[j] + xd[j];
        float m = fmaxf(fmaxf(xa[j], xb[j]), fmaxf(xc[j], xd[j]));
#pragma unroll
        for (int off = 16; off >= 1; off >>= 1) {
            s += __shfl_xor(s, off);
            m = fmaxf(m, __shfl_xor(m, off));
        }
        if (lane == 0) {
            f2u t; t.f = make_float2(s * (1.0f / 128.0f), m);
            sdat[HALO][c + HALO] = t.f;
            __hip_atomic_store(&stats[(size_t)wid * Wn + c], t.u,
                               __ATOMIC_RELAXED, __HIP_MEMORY_SCOPE_AGENT);
        }
    }

    // Pin the row's x in registers (no rematerialization from memory).
#pragma unroll
    for (int j = 0; j < 14; ++j)
        asm volatile("" : "+v"(xa[j]), "+v"(xb[j]), "+v"(xc[j]), "+v"(xd[j]));

    asm volatile("s_waitcnt vmcnt(0)" ::: "memory");     // stats stores complete
    __syncthreads();
    if (tid == 0)
        __hip_atomic_store(&flags[wid], 1, __ATOMIC_RELAXED, __HIP_MEMORY_SCOPE_AGENT);

    // ---- P2: per-group poll + load (overlaps backward loads w/ fwd waits) --
    if (grp < 7 && grp != HALO) {
        const int rr = r - HALO + grp;                   // image row for window row grp
        if (rr < 0 || rr >= Hn) {
            if (lane == 0) rowstate[grp] = 2;            // zero padding row
        } else {
            const int f = wid - HALO + grp;
            int got = 0;
            if (lane == 0) {
                got = __hip_atomic_load(&flags[f], __ATOMIC_RELAXED,
                                        __HIP_MEMORY_SCOPE_AGENT);
                int it = 0;
                while (!got && ++it < SPIN_MAX) {
                    __builtin_amdgcn_s_sleep(4);         // ~107ns, frees SIMD
                    got = __hip_atomic_load(&flags[f], __ATOMIC_RELAXED,
                                            __HIP_MEMORY_SCOPE_AGENT);
                }
                rowstate[grp] = got ? 1 : 3;
            }
            got = __shfl(got, 0, 32);                    // broadcast within group
            if (got) {
                const size_t srow = (size_t)(wid - HALO + grp) * Wn;
#pragma unroll
                for (int q = 0; q < 4; ++q) {
                    const int c = lane + 32 * q;
                    if (c < Wn) {
                        f2u t;
                        t.u = __hip_atomic_load(&stats[srow + c], __ATOMIC_RELAXED,
                                                __HIP_MEMORY_SCOPE_AGENT);
                        sdat[grp][c + HALO] = t.f;
                    }
                }
            }
        }
    } else if (grp == HALO && lane == 0) {
        rowstate[HALO] = 0;                              // own row already in LDS
    }
    __syncthreads();

    // ---- P2c: fallback recompute for unpublished rows (rare, correct) ------
    for (int kr = 0; kr < 7; ++kr) {
        if (rowstate[kr] != 3) continue;                 // uniform across block
        const int rr = r - HALO + kr;
        const size_t rb = ((size_t)(b * Hn + rr)) * Wn * 32;
        for (int pc = grp; pc < Wn; pc += 8) {
            const floatx4 v = x4[rb + (size_t)pc * 32 + lane];
            float s = v.x + v.y + v.z + v.w;
            float m = fmaxf(fmaxf(v.x, v.y), fmaxf(v.z, v.w));
#pragma unroll
            for (int off = 16; off >= 1; off >>= 1) {
                s += __shfl_xor(s, off);
                m = fmaxf(m, __shfl_xor(m, off));
            }
            if (lane == 0) sdat[kr][pc + HALO] = make_float2(s * (1.0f / 128.0f), m);
        }
    }
    if (rowstate[0] == 3 || rowstate[1] == 3 || rowstate[2] == 3 ||
        rowstate[4] == 3 || rowstate[5] == 3 || rowstate[6] == 3)
        __syncthreads();                                 // only on the rare path

    // ---- P3: 7x7 conv + bias + sigmoid -> gate ------------------------------
    if (tid < Wn) {
        float acc = bias[0];
#pragma unroll
        for (int kh = 0; kh < 7; ++kh)
#pragma unroll
            for (int kw = 0; kw < 7; ++kw) {
                const float2 sv = sdat[kh][tid + kw];
                acc = fmaf(sv.x, w[(kh * 7 + kw) * 2 + 0], acc);
                acc = fmaf(sv.y, w[(kh * 7 + kw) * 2 + 1], acc);
            }
        glds[tid] = 1.0f / (1.0f + expf(-acc));
    }
    __syncthreads();

    // ---- P4: out = x(reg) * gate, NT store (x never re-read) ---------------
    floatx4* __restrict__ o4 = reinterpret_cast<floatx4*>(out);
#pragma unroll
    for (int j = 0; j < 14; ++j) {
        const int c = grp + 8 * j;
        const float g = glds[c];
        floatx4 v;
        v.x = xa[j] * g; v.y = xb[j] * g; v.z = xc[j] * g; v.w = xd[j] * g;
        __builtin_nontemporal_store(v, &o4[rowbase + (size_t)c * 32 + lane]);
    }
}

extern "C" void kernel_launch(void* const* d_in, const int* in_sizes, int n_in,
                              void* d_out, int out_size, void* d_ws, size_t ws_size,
                              hipStream_t stream) {
    const float* x  = (const float*)d_in[0];
    const float* Wc = (const float*)d_in[1];
    const float* bb = (const float*)d_in[2];
    float* out = (float*)d_out;

    // workspace: stats u64[NROWS*Wn] (3.2 MB) then flags int[NROWS] (14 KB)
    unsigned long long* stats = (unsigned long long*)d_ws;
    int* flags = (int*)((char*)d_ws + (size_t)NROWS * Wn * sizeof(unsigned long long));

    hipMemsetAsync(flags, 0, NROWS * sizeof(int), stream);
    fused_reg_kernel<<<NROWS, 256, 0, stream>>>(x, Wc, bb, stats, flags, out);
}

// Round 14
// 85.038 us; speedup vs baseline: 1.0458x; 1.0458x over previous
//
#include <hip/hip_runtime.h>

// Problem constants: x [32,112,112,128] fp32, W [7,7,2,1] HWIO, b [1]
static constexpr int Bn = 32;
static constexpr int Hn = 112;
static constexpr int Wn = 112;
static constexpr int HALO = 3;
static constexpr int NROWS = Bn * Hn;          // 3584 blocks, block = one image row
static constexpr int SPIN_MAX = 100;           // with s_sleep(16): ~40us, then fallback

typedef float floatx4 __attribute__((ext_vector_type(4)));

union f2u { float2 f; unsigned long long u; };

// ---------------------------------------------------------------------------
// R12 EXACT REVERT (best measured: 85.1us). Producer-consumer fused kernel,
// block = one image row, register-resident x, relaxed-atomic stats publish,
// s_sleep-backoff spin, recompute fallback, NT stores.
//
//  P0: own-row x -> registers (14 float4/thread), issued first.
//  P1: stats (mean,max over 128ch) from regs -> LDS + global via RELAXED
//      agent-scope u64 stores (straight to MALL, no cache maintenance);
//      pin regs with asm; s_waitcnt vmcnt(0) + barrier; publish flag.
//  P2: spin with backoff on 6 neighbor flags; timeout -> recompute row
//      from x (identical values => correct under any dispatch schedule).
//  P3: 7x7x2 conv + bias + sigmoid -> gate in LDS.
//  P4: out = x(reg) * gate, non-temporal store. x never re-read.
//
// Ledger of refuted levers: occupancy (R11: 81% occ, slower), tight-poll
// fabric cost (R12: backoff = -3.2us only), P2 load overlap (R13: -3.8us
// regression). Residual ~13us over the ~72us mixed-stream floor is the
// intrinsic forward-dep publish latency of the single-pass structure.
// ---------------------------------------------------------------------------
__global__ __launch_bounds__(256) void fused_reg_kernel(const float* __restrict__ x,
                                                        const float* __restrict__ Wc,
                                                        const float* __restrict__ bias,
                                                        unsigned long long* __restrict__ stats,
                                                        int* __restrict__ flags,
                                                        float* __restrict__ out) {
    __shared__ float2 sdat[7][Wn + 2 * HALO];  // zero-padded stat tile (6.6 KB)
    __shared__ float  glds[Wn];
    __shared__ float  w[98];
    __shared__ int    rowstate[7];             // 0=own,1=from global,2=zero,3=recompute

    const int wid  = blockIdx.x;               // == b*Hn + r
    const int b    = wid / Hn;
    const int r    = wid % Hn;
    const int tid  = threadIdx.x;
    const int lane = tid & 31;
    const int grp  = tid >> 5;                 // 8 groups; group = one pixel (32 float4)

    const floatx4* __restrict__ x4 = reinterpret_cast<const floatx4*>(x);
    const size_t rowbase = (size_t)wid * Wn * 32;        // float4 units

    // ---- P0: own-row x -> registers (issued first, hides HBM latency) -----
    float xa[14], xb[14], xc[14], xd[14];
#pragma unroll
    for (int j = 0; j < 14; ++j) {
        const int c = grp + 8 * j;
        const floatx4 v = x4[rowbase + (size_t)c * 32 + lane];
        xa[j] = v.x; xb[j] = v.y; xc[j] = v.z; xd[j] = v.w;
    }

    if (tid < 98) w[tid] = Wc[tid];
    for (int i = tid; i < 7 * (Wn + 2 * HALO); i += 256)
        ((float2*)sdat)[i] = make_float2(0.f, 0.f);
    __syncthreads();

    // ---- P1: own-row stats from registers -> LDS + global (relaxed) -------
#pragma unroll
    for (int j = 0; j < 14; ++j) {
        const int c = grp + 8 * j;
        float s = xa[j] + xb[j] + xc[j] + xd[j];
        float m = fmaxf(fmaxf(xa[j], xb[j]), fmaxf(xc[j], xd[j]));
#pragma unroll
        for (int off = 16; off >= 1; off >>= 1) {
            s += __shfl_xor(s, off);
            m = fmaxf(m, __shfl_xor(m, off));
        }
        if (lane == 0) {
            f2u t; t.f = make_float2(s * (1.0f / 128.0f), m);
            sdat[HALO][c + HALO] = t.f;
            __hip_atomic_store(&stats[(size_t)wid * Wn + c], t.u,
                               __ATOMIC_RELAXED, __HIP_MEMORY_SCOPE_AGENT);
        }
    }

    // Pin the row's x in registers (no rematerialization from memory).
#pragma unroll
    for (int j = 0; j < 14; ++j)
        asm volatile("" : "+v"(xa[j]), "+v"(xb[j]), "+v"(xc[j]), "+v"(xd[j]));

    asm volatile("s_waitcnt vmcnt(0)" ::: "memory");     // stats stores complete
    __syncthreads();
    if (tid == 0)
        __hip_atomic_store(&flags[wid], 1, __ATOMIC_RELAXED, __HIP_MEMORY_SCOPE_AGENT);

    // ---- P2a: lane-parallel spin with s_sleep backoff ----------------------
    if (tid < 7) {
        int st = 0;                                      // own row
        if (tid != HALO) {
            const int rr = r - HALO + tid;
            if (rr < 0 || rr >= Hn) st = 2;              // zero-padding row
            else {
                const int f = wid - HALO + tid;
                int got = __hip_atomic_load(&flags[f], __ATOMIC_RELAXED,
                                            __HIP_MEMORY_SCOPE_AGENT);
                int it = 0;
                while (!got && ++it < SPIN_MAX) {
                    __builtin_amdgcn_s_sleep(16);        // ~1k clocks, frees SIMD
                    got = __hip_atomic_load(&flags[f], __ATOMIC_RELAXED,
                                            __HIP_MEMORY_SCOPE_AGENT);
                }
                st = got ? 1 : 3;
            }
        }
        rowstate[tid] = st;
    }
    __syncthreads();

    // ---- P2b: bulk-load published halo stats (relaxed u64 from MALL) -------
    for (int p = tid; p < 7 * Wn; p += 256) {
        const int kr = p / Wn;
        const int c  = p % Wn;
        if (rowstate[kr] == 1) {
            f2u t;
            t.u = __hip_atomic_load(&stats[(size_t)(wid - HALO + kr) * Wn + c],
                                    __ATOMIC_RELAXED, __HIP_MEMORY_SCOPE_AGENT);
            sdat[kr][c + HALO] = t.f;
        }
    }
    // ---- P2c: fallback recompute for unpublished rows (rare, correct) ------
    for (int kr = 0; kr < 7; ++kr) {
        if (rowstate[kr] != 3) continue;                 // uniform across block
        const int rr = r - HALO + kr;
        const size_t rb = ((size_t)(b * Hn + rr)) * Wn * 32;
        for (int pc = grp; pc < Wn; pc += 8) {
            const floatx4 v = x4[rb + (size_t)pc * 32 + lane];
            float s = v.x + v.y + v.z + v.w;
            float m = fmaxf(fmaxf(v.x, v.y), fmaxf(v.z, v.w));
#pragma unroll
            for (int off = 16; off >= 1; off >>= 1) {
                s += __shfl_xor(s, off);
                m = fmaxf(m, __shfl_xor(m, off));
            }
            if (lane == 0) sdat[kr][pc + HALO] = make_float2(s * (1.0f / 128.0f), m);
        }
    }
    __syncthreads();

    // ---- P3: 7x7 conv + bias + sigmoid -> gate ------------------------------
    if (tid < Wn) {
        float acc = bias[0];
#pragma unroll
        for (int kh = 0; kh < 7; ++kh)
#pragma unroll
            for (int kw = 0; kw < 7; ++kw) {
                const float2 sv = sdat[kh][tid + kw];
                acc = fmaf(sv.x, w[(kh * 7 + kw) * 2 + 0], acc);
                acc = fmaf(sv.y, w[(kh * 7 + kw) * 2 + 1], acc);
            }
        glds[tid] = 1.0f / (1.0f + expf(-acc));
    }
    __syncthreads();

    // ---- P4: out = x(reg) * gate, NT store (x never re-read) ---------------
    floatx4* __restrict__ o4 = reinterpret_cast<floatx4*>(out);
#pragma unroll
    for (int j = 0; j < 14; ++j) {
        const int c = grp + 8 * j;
        const float g = glds[c];
        floatx4 v;
        v.x = xa[j] * g; v.y = xb[j] * g; v.z = xc[j] * g; v.w = xd[j] * g;
        __builtin_nontemporal_store(v, &o4[rowbase + (size_t)c * 32 + lane]);
    }
}

extern "C" void kernel_launch(void* const* d_in, const int* in_sizes, int n_in,
                              void* d_out, int out_size, void* d_ws, size_t ws_size,
                              hipStream_t stream) {
    const float* x  = (const float*)d_in[0];
    const float* Wc = (const float*)d_in[1];
    const float* bb = (const float*)d_in[2];
    float* out = (float*)d_out;

    // workspace: stats u64[NROWS*Wn] (3.2 MB) then flags int[NROWS] (14 KB)
    unsigned long long* stats = (unsigned long long*)d_ws;
    int* flags = (int*)((char*)d_ws + (size_t)NROWS * Wn * sizeof(unsigned long long));

    hipMemsetAsync(flags, 0, NROWS * sizeof(int), stream);
    fused_reg_kernel<<<NROWS, 256, 0, stream>>>(x, Wc, bb, stats, flags, out);
}